// Round 1
// baseline (168.247 us; speedup 1.0000x reference)
//
#include <hip/hip_runtime.h>

// GCN on a directed chain i->i+1 with self-loops.
// Stencil coefficients (from symmetric normalization):
//   deg[0]=1, deg[j>=1]=2  ->  dis[0]=1, dis[j>=1]=1/sqrt(2)
//   out[j] = a_j*h[j] + c_j*h[j-1],  a_0=1, a_j=0.5 (j>=1)
//   c_0=0, c_1=1/sqrt(2), c_j=0.5 (j>=2)
// Layer 3 fuses: stencil(h2@W3)+b3 == (stencil(h2))@W3 + b3  (linearity).

#define N_NODES 8192
#define F_IN 4
#define H1 32
#define H2 16

__device__ __forceinline__ float coefA(int j) { return j == 0 ? 1.0f : 0.5f; }
__device__ __forceinline__ float coefC(int j) {
    return j <= 0 ? 0.0f : (j == 1 ? 0.70710678118654752f : 0.5f);
}

// ---------------- front: x -> g = stencil(h2), [N,16] ----------------
__global__ void __launch_bounds__(256) gnn_front(
    const float* __restrict__ x,  const float* __restrict__ W1, const float* __restrict__ b1,
    const float* __restrict__ W2, const float* __restrict__ b2, float* __restrict__ g)
{
    __shared__ float sW1[F_IN * H1];   // 128
    __shared__ float sW2[H1 * H2];     // 512
    __shared__ float sb1[H1];
    __shared__ float sb2[H2];
    const int t = threadIdx.x;
    if (t < F_IN * H1) sW1[t] = W1[t];
    if (t < H1) sb1[t] = b1[t];
    if (t < H2) sb2[t] = b2[t];
    sW2[t] = W2[t];
    sW2[t + 256] = W2[t + 256];
    __syncthreads();

    const int j = blockIdx.x * blockDim.x + t;
    if (j >= N_NODES) return;

    // t1 row for node jj (zeros if jj < 0); garbage at jj<0 is killed by c_0=0 later.
    auto t1row = [&](int jj, float* out32) {
        float4 xr = make_float4(0.f, 0.f, 0.f, 0.f);
        if (jj >= 0) xr = *reinterpret_cast<const float4*>(&x[jj * F_IN]);
        #pragma unroll
        for (int k = 0; k < H1; ++k) {
            out32[k] = xr.x * sW1[0 * H1 + k] + xr.y * sW1[1 * H1 + k]
                     + xr.z * sW1[2 * H1 + k] + xr.w * sW1[3 * H1 + k];
        }
    };

    float tA[H1], tB[H1];
    float t2m2[H2], t2m1[H2], t2c[H2];

    t1row(j - 3, tA);
    float* prev = tA;
    float* cur  = tB;
    float* t2out[3] = { t2m2, t2m1, t2c };
    #pragma unroll
    for (int s = 0; s < 3; ++s) {
        const int jj = j - 2 + s;     // node index of the h1/t2 row being built
        t1row(jj, cur);
        const float a = coefA(jj), c = coefC(jj);
        float h1r[H1];
        #pragma unroll
        for (int k = 0; k < H1; ++k) {
            float v = a * cur[k] + c * prev[k] + sb1[k];
            h1r[k] = v > 0.f ? v : 0.f;
        }
        #pragma unroll
        for (int m = 0; m < H2; ++m) {
            float acc = 0.f;
            #pragma unroll
            for (int k = 0; k < H1; ++k) acc += h1r[k] * sW2[k * H2 + m];
            t2out[s][m] = acc;
        }
        float* tmp = prev; prev = cur; cur = tmp;
    }

    const float aj = coefA(j),     cj = coefC(j);
    const float ap = coefA(j - 1), cp = coefC(j - 1);
    float gout[H2];
    #pragma unroll
    for (int m = 0; m < H2; ++m) {
        float h2c = aj * t2c[m]  + cj * t2m1[m] + sb2[m];
        h2c = h2c > 0.f ? h2c : 0.f;
        float h2p = ap * t2m1[m] + cp * t2m2[m] + sb2[m];
        h2p = h2p > 0.f ? h2p : 0.f;
        gout[m] = aj * h2c + cj * h2p;           // g[j] = stencil(h2)[j]
    }
    #pragma unroll
    for (int m = 0; m < H2; m += 4) {
        *reinterpret_cast<float4*>(&g[j * H2 + m]) =
            make_float4(gout[m], gout[m + 1], gout[m + 2], gout[m + 3]);
    }
}

// ---------------- out = g @ W3 + b3, [N, N] ----------------
#define COLS_PER_BLOCK 1024   // 256 threads * float4
#define ROWS_PER_BLOCK 64

__global__ void __launch_bounds__(256) gnn_out(
    const float* __restrict__ g, const float* __restrict__ W3,
    const float* __restrict__ b3, float* __restrict__ out)
{
    __shared__ float gs[ROWS_PER_BLOCK][H2];   // 4 KB
    const int t = threadIdx.x;
    const int col0 = blockIdx.x * COLS_PER_BLOCK + t * 4;
    const int row0 = blockIdx.y * ROWS_PER_BLOCK;

    // stage g rows for this row tile (coalesced)
    #pragma unroll
    for (int i = 0; i < (ROWS_PER_BLOCK * H2) / 256; ++i) {
        const int idx = i * 256 + t;
        reinterpret_cast<float*>(gs)[idx] = g[row0 * H2 + idx];
    }
    __syncthreads();

    // W3 column slab in registers: 16 x float4 = 64 VGPRs, loaded once per block
    float4 w[H2];
    #pragma unroll
    for (int k = 0; k < H2; ++k)
        w[k] = *reinterpret_cast<const float4*>(&W3[k * N_NODES + col0]);
    const float4 bb = *reinterpret_cast<const float4*>(&b3[col0]);

    for (int r = 0; r < ROWS_PER_BLOCK; ++r) {
        float4 acc = bb;
        #pragma unroll
        for (int k = 0; k < H2; ++k) {
            const float gv = gs[r][k];   // wave-uniform broadcast
            acc.x += gv * w[k].x;
            acc.y += gv * w[k].y;
            acc.z += gv * w[k].z;
            acc.w += gv * w[k].w;
        }
        *reinterpret_cast<float4*>(&out[(size_t)(row0 + r) * N_NODES + col0]) = acc;
    }
}

extern "C" void kernel_launch(void* const* d_in, const int* in_sizes, int n_in,
                              void* d_out, int out_size, void* d_ws, size_t ws_size,
                              hipStream_t stream) {
    const float* x  = (const float*)d_in[0];
    const float* W1 = (const float*)d_in[1];
    const float* b1 = (const float*)d_in[2];
    const float* W2 = (const float*)d_in[3];
    const float* b2 = (const float*)d_in[4];
    const float* W3 = (const float*)d_in[5];
    const float* b3 = (const float*)d_in[6];
    // d_in[7] = edge_index: fixed directed chain i->i+1 (structure hardcoded above)

    float* g   = (float*)d_ws;            // [N_NODES, H2] = 512 KB
    float* out = (float*)d_out;

    gnn_front<<<N_NODES / 256, 256, 0, stream>>>(x, W1, b1, W2, b2, g);

    dim3 grid(N_NODES / COLS_PER_BLOCK, N_NODES / ROWS_PER_BLOCK);  // 8 x 128
    gnn_out<<<grid, 256, 0, stream>>>(g, W3, b3, out);
}